// Round 1
// 757.054 us; speedup vs baseline: 1.1029x; 1.1029x over previous
//
#include <hip/hip_runtime.h>
#include <hip/hip_bf16.h>
#include <cstdint>
#include <cstddef>

typedef __bf16 bf16_t;
typedef __bf16 bf16x4 __attribute__((ext_vector_type(4)));
typedef __bf16 bf16x8 __attribute__((ext_vector_type(8)));
typedef float f32x4 __attribute__((ext_vector_type(4)));

#define D_EMB   4096
#define N_HEADS 32
#define HEAD_D  128
#define SEQ     64
#define NBATCH  32
#define MTOT    2048
#define MB      1048576ULL
#define N4X     2097152   // MTOT*D_EMB/4  (2^21)
#define N4W     4194304   // D_EMB*D_EMB/4 (2^22)

// ---------------- fused fp32 -> bf16 convert: x + 5 weights, one launch ----
__global__ __launch_bounds__(256) void cvt_all(
    const float* __restrict__ x,  const float* __restrict__ w0,
    const float* __restrict__ w1, const float* __restrict__ w2,
    const float* __restrict__ w3, const float* __restrict__ w4,
    bf16_t* __restrict__ xb, bf16_t* __restrict__ d0, bf16_t* __restrict__ d1,
    bf16_t* __restrict__ d2, bf16_t* __restrict__ d3, bf16_t* __restrict__ d4) {
  const int i = blockIdx.x * 256 + threadIdx.x;
  const float* s; bf16_t* d; int j;
  if (i < N4X) { s = x; d = xb; j = i; }
  else {
    const int r = i - N4X;
    const int wi = r >> 22;          // / N4W
    j = r & (N4W - 1);
    if (wi == 0)      { s = w0; d = d0; }
    else if (wi == 1) { s = w1; d = d1; }
    else if (wi == 2) { s = w2; d = d2; }
    else if (wi == 3) { s = w3; d = d3; }
    else              { s = w4; d = d4; }
  }
  const float4 v = ((const float4*)s)[j];
  bf16x4 o;
  o[0] = (bf16_t)v.x; o[1] = (bf16_t)v.y; o[2] = (bf16_t)v.z; o[3] = (bf16_t)v.w;
  ((bf16x4*)d)[j] = o;
}

// ---------------- async global->LDS (16B per lane) ----------------
__device__ __forceinline__ void lds_async16(void* lds, const void* gp) {
  __builtin_amdgcn_global_load_lds(
      (const __attribute__((address_space(1))) void*)gp,
      (__attribute__((address_space(3))) void*)lds, 16, 0, 0);
}

#define BARRIER() asm volatile("s_barrier" ::: "memory")
#define WAIT_LGKM0()                                          \
  do {                                                        \
    asm volatile("s_waitcnt lgkmcnt(0)" ::: "memory");        \
    __builtin_amdgcn_sched_barrier(0);                        \
  } while (0)
#define WAIT_VM(n) asm volatile("s_waitcnt vmcnt(" #n ")" ::: "memory")

// =====================================================================
// Stage 1: fused 4-way projection GEMM — 256x256 tile, BK=64, 8 waves,
// double-buffered 128KiB LDS, 4-phase-per-K-tile counted-vmcnt schedule
// (T1 xcd-swizzle + T2 LDS swizzle + T3/T4 phases w/ counted vmcnt + T5).
//
// LDS layout per buffer (64KB): A tile [ks=2][256 rows][32 bf16 = 64B],
// then B tile same, where ks indexes the two k=32 halves of BK=64.
// Swizzle: physical = linear ^ (((linear>>7)&3)<<4)  (row bits 1..2 ->
// byte bits 4..5). Verified bijective per 8-lane beat group -> conflict-
// free ds_read_b128. global_load_lds writes linearly, so the GLOBAL
// source address is pre-permuted with the same involution (rule #21).
//
// Staging schedule (per-thread, 2 loads per region slot):
//   phase1 of tile T: issue A.ks0(T+1)      (into buf^1)
//   phase2:           issue A.ks1(T+1), B.ks0(T+2)  (B into buf: safe,
//                     tile T's B-reads completed at phase1 lgkmcnt(0))
//   phase3:           issue B.ks1(T+2)
//   phase4:           MFMA; s_waitcnt vmcnt(4); s_barrier
// vmcnt(4) leaves exactly B(T+2)'s 4 loads in flight while guaranteeing
// all of tile T+1 landed — counted, never drained to 0 in the loop.
// =====================================================================

#define READ_A(Q)                                                           \
  do {                                                                      \
    _Pragma("unroll")                                                       \
    for (int mi = 0; mi < 2; ++mi) {                                        \
      _Pragma("unroll")                                                     \
      for (int ks = 0; ks < 2; ++ks) {                                      \
        afr[mi][ks] =                                                       \
            *(const bf16x8*)(As + aoff + ((Q) * 2 + mi) * 1024 + ks * 16384); \
      }                                                                     \
    }                                                                       \
  } while (0)

#define MFMA_PHASE(Q)                                                       \
  do {                                                                      \
    __builtin_amdgcn_s_setprio(1);                                          \
    _Pragma("unroll")                                                       \
    for (int mi = 0; mi < 2; ++mi) {                                        \
      _Pragma("unroll")                                                     \
      for (int j = 0; j < 4; ++j) {                                         \
        _Pragma("unroll")                                                   \
        for (int ks = 0; ks < 2; ++ks) {                                    \
          acc[(Q) * 2 + mi][j] = __builtin_amdgcn_mfma_f32_16x16x32_bf16(   \
              afr[mi][ks], bfr[j][ks], acc[(Q) * 2 + mi][j], 0, 0, 0);      \
        }                                                                   \
      }                                                                     \
    }                                                                       \
    __builtin_amdgcn_s_setprio(0);                                          \
  } while (0)

__global__ __launch_bounds__(512, 2) void proj_gemm8(
    const bf16_t* __restrict__ x,
    const bf16_t* __restrict__ Wq, const float* __restrict__ bq,
    const bf16_t* __restrict__ Wk, const float* __restrict__ bk,
    const bf16_t* __restrict__ Wv, const float* __restrict__ bv_,
    const bf16_t* __restrict__ Wd, const float* __restrict__ bd,
    bf16_t* __restrict__ Qp, bf16_t* __restrict__ Kp,
    bf16_t* __restrict__ Vp, bf16_t* __restrict__ Gp) {
  __shared__ __align__(16) char smem[131072];

  const int tid  = threadIdx.x;
  const int lane = tid & 63;
  const int wave = tid >> 6;
  const int quad = lane >> 4, l16 = lane & 15;
  const int wm = wave >> 2, wn = wave & 3;   // 2x4 wave grid -> 128x64 per wave

  // XCD-aware swizzle over the 512-block grid (512 % 8 == 0 -> bijective)
  const int bid = (int)blockIdx.x;
  const int sw  = ((bid & 7) << 6) | (bid >> 3);
  const int mt  = sw & 7;          // 8 m-tiles
  const int nt  = sw >> 3;         // 64 n-tiles (4 mats x 16)
  const int m0  = mt << 8;
  const int mat = nt >> 4;
  const int n0  = (nt & 15) << 8;

  const bf16_t* Bw; const float* bias; bf16_t* dst;
  if (mat == 0)      { Bw = Wq; bias = bq;  dst = Qp; }
  else if (mat == 1) { Bw = Wk; bias = bk;  dst = Kp; }
  else if (mat == 2) { Bw = Wv; bias = bv_; dst = Vp; }
  else               { Bw = Wd; bias = bd;  dst = Gp; }

  // ---- staging addressing: per-thread 2 chunks of 16B per 16KB region ----
  const int p0 = tid * 16, p1 = p0 + 8192;
  const int o0 = p0 ^ (((p0 >> 7) & 3) << 4);
  const int o1 = p1 ^ (((p1 >> 7) & 3) << 4);
  const char* gA0 = (const char*)(x  + (size_t)(m0 + (o0 >> 6)) * D_EMB) + (o0 & 63);
  const char* gA1 = (const char*)(x  + (size_t)(m0 + (o1 >> 6)) * D_EMB) + (o1 & 63);
  const char* gB0 = (const char*)(Bw + (size_t)(n0 + (o0 >> 6)) * D_EMB) + (o0 & 63);
  const char* gB1 = (const char*)(Bw + (size_t)(n0 + (o1 >> 6)) * D_EMB) + (o1 & 63);

  auto stageA = [&](int nb, int ks, int kbyte) {
    char* d = smem + nb * 65536 + ks * 16384;
    lds_async16(d + p0, gA0 + kbyte + ks * 64);
    lds_async16(d + p1, gA1 + kbyte + ks * 64);
  };
  auto stageB = [&](int nb, int ks, int kbyte) {
    char* d = smem + nb * 65536 + 32768 + ks * 16384;
    lds_async16(d + p0, gB0 + kbyte + ks * 64);
    lds_async16(d + p1, gB1 + kbyte + ks * 64);
  };

  // ---- LDS read offsets (swizzle folds to a per-lane constant) ----
  const int qsw  = (quad << 4) ^ ((l16 & 6) << 3);
  const int aoff = (wm * 128 + l16) * 64 + qsw;            // + mi*1024 + ks*16384
  const int boff = 32768 + (wn * 64 + l16) * 64 + qsw;     // + j*1024 + ks*16384

  f32x4 acc[8][4];
  const f32x4 zero = {0.f, 0.f, 0.f, 0.f};
#pragma unroll
  for (int i = 0; i < 8; ++i)
#pragma unroll
    for (int j = 0; j < 4; ++j) acc[i][j] = zero;

  // ---- prologue: tile0 fully + tile1's B; allow B(1) (4 loads) in flight ----
  stageA(0, 0, 0); stageA(0, 1, 0);
  stageB(0, 0, 0); stageB(0, 1, 0);
  stageB(1, 0, 128); stageB(1, 1, 128);
  WAIT_VM(4);
  BARRIER();

  bf16x8 bfr[4][2], afr[2][2];

#pragma unroll 1
  for (int T = 0; T < 64; ++T) {
    const int buf = T & 1;
    const char* As = smem + buf * 65536;
    const int kb1 = (T + 1) << 7;   // byte offset of K-tile T+1
    const int kb2 = (T + 2) << 7;

    // ---------- phase 1: read all B-frags + A quadrant 0; stage A.ks0(T+1)
#pragma unroll
    for (int j = 0; j < 4; ++j)
#pragma unroll
      for (int ks = 0; ks < 2; ++ks)
        bfr[j][ks] = *(const bf16x8*)(As + boff + j * 1024 + ks * 16384);
    READ_A(0);
    if (T < 63) stageA(buf ^ 1, 0, kb1);
    BARRIER();
    WAIT_LGKM0();
    MFMA_PHASE(0);
    BARRIER();

    // ---------- phase 2: A quadrant 1; stage A.ks1(T+1), B.ks0(T+2)
    READ_A(1);
    if (T < 63) stageA(buf ^ 1, 1, kb1);
    if (T < 62) stageB(buf, 0, kb2);
    BARRIER();
    WAIT_LGKM0();
    MFMA_PHASE(1);
    BARRIER();

    // ---------- phase 3: A quadrant 2; stage B.ks1(T+2)
    READ_A(2);
    if (T < 62) stageB(buf, 1, kb2);
    BARRIER();
    WAIT_LGKM0();
    MFMA_PHASE(2);
    BARRIER();

    // ---------- phase 4: A quadrant 3; counted vmcnt; tile boundary
    READ_A(3);
    BARRIER();
    WAIT_LGKM0();
    MFMA_PHASE(3);
    if (T < 62) { WAIT_VM(4); } else { WAIT_VM(0); }
    BARRIER();
  }

  // ---- epilogue: bias (+sigmoid for gamma), store bf16 ----
  const bool is_g = (mat == 3);
#pragma unroll
  for (int j = 0; j < 4; ++j) {
    const int col = n0 + wn * 64 + j * 16 + l16;
    const float bb = bias[col];
#pragma unroll
    for (int mi = 0; mi < 8; ++mi) {
      const int rowb = m0 + wm * 128 + mi * 16 + quad * 4;
#pragma unroll
      for (int r = 0; r < 4; ++r) {
        float v = acc[mi][j][r] + bb;
        if (is_g) v = 1.0f / (1.0f + __expf(-v));
        dst[(size_t)(rowb + r) * D_EMB + col] = (bf16_t)v;
      }
    }
  }
}

// ---------------- m97-style bt-GEMM core: C[128x128] tile (out_gemm) -------
__device__ __forceinline__ void gemm_core_bt(const bf16_t* __restrict__ A,
                                             const bf16_t* __restrict__ B,
                                             int K, int m0, int n0,
                                             bf16_t* As, bf16_t* Bs,
                                             f32x4 acc[4][4]) {
  const int tid  = threadIdx.x;
  const int lane = tid & 63;
  const int wave = tid >> 6;
  const int quad = lane >> 4;
  const int l16  = lane & 15;
  const int wm   = (wave >> 1) * 64;
  const int wn   = (wave & 1) * 64;

  const int q0 = tid;
  const int q1 = tid + 256;
  const int r0 = q0 >> 2, c0 = (q0 & 3) * 8;
  const int r1 = q1 >> 2, c1 = (q1 & 3) * 8;

  const bf16_t* Arow0 = A + (size_t)(m0 + r0) * K + c0;
  const bf16_t* Arow1 = A + (size_t)(m0 + r1) * K + c1;
  const bf16_t* Brow0 = B + (size_t)(n0 + r0) * K + c0;
  const bf16_t* Brow1 = B + (size_t)(n0 + r1) * K + c1;

  for (int k0 = 0; k0 < K; k0 += 32) {
    lds_async16(As + q0 * 8, Arow0 + k0);
    lds_async16(As + q1 * 8, Arow1 + k0);
    lds_async16(Bs + q0 * 8, Brow0 + k0);
    lds_async16(Bs + q1 * 8, Brow1 + k0);
    __syncthreads();

    bf16x8 af[4], bfv[4];
#pragma unroll
    for (int i = 0; i < 4; i++)
      af[i] = *(const bf16x8*)&As[(wm + 16 * i + l16) * 32 + quad * 8];
#pragma unroll
    for (int j = 0; j < 4; j++)
      bfv[j] = *(const bf16x8*)&Bs[(wn + 16 * j + l16) * 32 + quad * 8];
#pragma unroll
    for (int i = 0; i < 4; i++)
#pragma unroll
      for (int j = 0; j < 4; j++)
        acc[i][j] = __builtin_amdgcn_mfma_f32_16x16x32_bf16(af[i], bfv[j],
                                                            acc[i][j], 0, 0, 0);
    __syncthreads();
  }
}

// ---------------- Stage 2: per-(b,h) RoPE + decay + attention (MFMA) -------
__global__ __launch_bounds__(256) void attn_kernel(
    const bf16_t* __restrict__ Qp, const bf16_t* __restrict__ Kp,
    const bf16_t* __restrict__ Vp, const bf16_t* __restrict__ Gp,
    const float* __restrict__ t, bf16_t* __restrict__ attn) {
  __shared__ __align__(16) char smem[65536];
  bf16_t* Qs  = (bf16_t*)smem;              // [64][128] rope(Q)
  bf16_t* Ks  = (bf16_t*)(smem + 16384);    // [64][128] rope(K)
  bf16_t* Gs  = (bf16_t*)(smem + 32768);    // [64][128] gc
  bf16_t* IGs = (bf16_t*)(smem + 49152);    // [64][128] 1/gc
  // phase-3 overlay (over Gs/IGs):
  bf16_t* Ps  = (bf16_t*)(smem + 32768);           // [64][72] decayed, bf16
  bf16_t* Vt  = (bf16_t*)(smem + 32768 + 9216);    // [128][72] V transposed

  const int tid = threadIdx.x;
  const int lane = tid & 63, wv = tid >> 6;
  const int quad = lane >> 4, l16 = lane & 15;
  const int b = blockIdx.x >> 5, h = blockIdx.x & 31;
  const size_t base = (size_t)(b * SEQ) * D_EMB + (size_t)h * HEAD_D;

  for (int idx = tid; idx < SEQ * HEAD_D; idx += 256) {
    const int s = idx >> 7, d = idx & 127;
    const float invf = __expf(-0.14391156831212787f * (float)s);
    const float theta = t[d & 63] * invf;
    float sn, cs;
    __sincosf(theta, &sn, &cs);
    const size_t po = base + (size_t)s * D_EMB;
    {
      const float v = (float)Qp[po + d];
      const float o = (float)Qp[po + (d ^ 64)];
      const float rot = (d < 64) ? -o : o;
      Qs[idx] = (bf16_t)(v * cs + rot * sn);
    }
    {
      const float v = (float)Kp[po + d];
      const float o = (float)Kp[po + (d ^ 64)];
      const float rot = (d < 64) ? -o : o;
      Ks[idx] = (bf16_t)(v * cs + rot * sn);
    }
  }
  if (tid < HEAD_D) {
    const int d = tid;
    float run = 1.0f;
    for (int s = 0; s < SEQ; s++) {
      run *= (float)Gp[base + (size_t)s * D_EMB + d];
      Gs[s * HEAD_D + d]  = (bf16_t)run;
      IGs[s * HEAD_D + d] = (bf16_t)(1.0f / run);
    }
  }
  __syncthreads();

  f32x4 Sa[4], Da[4];
  const f32x4 zero = {0.f, 0.f, 0.f, 0.f};
#pragma unroll
  for (int j = 0; j < 4; j++) { Sa[j] = zero; Da[j] = zero; }

  for (int k0 = 0; k0 < HEAD_D; k0 += 32) {
    const bf16x8 aq = *(const bf16x8*)&Qs[(wv * 16 + l16) * HEAD_D + quad * 8 + k0];
    const bf16x8 ag = *(const bf16x8*)&Gs[(wv * 16 + l16) * HEAD_D + quad * 8 + k0];
#pragma unroll
    for (int j = 0; j < 4; j++) {
      const bf16x8 bk = *(const bf16x8*)&Ks [(16 * j + l16) * HEAD_D + quad * 8 + k0];
      const bf16x8 bg = *(const bf16x8*)&IGs[(16 * j + l16) * HEAD_D + quad * 8 + k0];
      Sa[j] = __builtin_amdgcn_mfma_f32_16x16x32_bf16(aq, bk, Sa[j], 0, 0, 0);
      Da[j] = __builtin_amdgcn_mfma_f32_16x16x32_bf16(ag, bg, Da[j], 0, 0, 0);
    }
  }
  __syncthreads();

#pragma unroll
  for (int j = 0; j < 4; j++) {
#pragma unroll
    for (int r = 0; r < 4; r++) {
      const int q = wv * 16 + quad * 4 + r;
      const int k = 16 * j + l16;
      const float v = (k <= q) ? Sa[j][r] * Da[j][r] * 0.0078125f : 0.0f;
      Ps[q * 72 + k] = (bf16_t)v;
    }
  }
  for (int idx = tid; idx < SEQ * HEAD_D; idx += 256) {
    const int s = idx >> 7, d = idx & 127;
    Vt[d * 72 + s] = Vp[base + (size_t)s * D_EMB + d];
  }
  __syncthreads();

  f32x4 oa[8];
#pragma unroll
  for (int j = 0; j < 8; j++) oa[j] = zero;
  for (int k0 = 0; k0 < SEQ; k0 += 32) {
    const bf16x8 ap = *(const bf16x8*)&Ps[(wv * 16 + l16) * 72 + quad * 8 + k0];
#pragma unroll
    for (int j = 0; j < 8; j++) {
      const bf16x8 bv = *(const bf16x8*)&Vt[(16 * j + l16) * 72 + quad * 8 + k0];
      oa[j] = __builtin_amdgcn_mfma_f32_16x16x32_bf16(ap, bv, oa[j], 0, 0, 0);
    }
  }
#pragma unroll
  for (int j = 0; j < 8; j++) {
#pragma unroll
    for (int r = 0; r < 4; r++) {
      const int q = wv * 16 + quad * 4 + r;
      attn[(size_t)(b * SEQ + q) * D_EMB + (size_t)h * HEAD_D + 16 * j + l16] =
          (bf16_t)oa[j][r];
    }
  }
}

// ---------------- Stage 3: output projection GEMM (fp32 out) ----------------
__global__ __launch_bounds__(256) void out_gemm(
    const bf16_t* __restrict__ A, const bf16_t* __restrict__ Wo,
    const float* __restrict__ bo, float* __restrict__ out) {
  __shared__ __align__(16) bf16_t As[128 * 32];
  __shared__ __align__(16) bf16_t Bs[128 * 32];

  const int m0 = blockIdx.x * 128;
  const int n0 = blockIdx.y * 128;

  f32x4 acc[4][4];
  const f32x4 zero = {0.f, 0.f, 0.f, 0.f};
#pragma unroll
  for (int i = 0; i < 4; i++)
#pragma unroll
    for (int j = 0; j < 4; j++) acc[i][j] = zero;

  gemm_core_bt(A, Wo, D_EMB, m0, n0, As, Bs, acc);

  const int tid = threadIdx.x, lane = tid & 63, wave = tid >> 6;
  const int quad = lane >> 4, l16 = lane & 15;
  const int wm = (wave >> 1) * 64, wn = (wave & 1) * 64;

#pragma unroll
  for (int i = 0; i < 4; i++) {
#pragma unroll
    for (int j = 0; j < 4; j++) {
      const int col = n0 + wn + 16 * j + l16;
      const float bv_ = bo[col];
      const int rowb = m0 + wm + 16 * i + quad * 4;
#pragma unroll
      for (int r = 0; r < 4; r++)
        out[(size_t)(rowb + r) * D_EMB + col] = acc[i][j][r] + bv_;
    }
  }
}

// ---------------- launch ----------------
extern "C" void kernel_launch(void* const* d_in, const int* in_sizes, int n_in,
                              void* d_out, int out_size, void* d_ws, size_t ws_size,
                              hipStream_t stream) {
  const float* x  = (const float*)d_in[0];
  const float* t  = (const float*)d_in[1];
  const float* Wq = (const float*)d_in[2];
  const float* bq = (const float*)d_in[3];
  const float* Wk = (const float*)d_in[4];
  const float* bk = (const float*)d_in[5];
  const float* Wv = (const float*)d_in[6];
  const float* bv = (const float*)d_in[7];
  const float* Wd = (const float*)d_in[8];
  const float* bd = (const float*)d_in[9];
  const float* Wo = (const float*)d_in[10];
  const float* bo = (const float*)d_in[11];

  char* ws = (char*)d_ws;
  bf16_t* xb   = (bf16_t*)(ws);
  bf16_t* Wqb  = (bf16_t*)(ws + 16 * MB);
  bf16_t* Wkb  = (bf16_t*)(ws + 48 * MB);
  bf16_t* Wvb  = (bf16_t*)(ws + 80 * MB);
  bf16_t* Wdb  = (bf16_t*)(ws + 112 * MB);
  bf16_t* Wob  = (bf16_t*)(ws + 144 * MB);
  bf16_t* Qp   = (bf16_t*)(ws + 176 * MB);
  bf16_t* Kp   = (bf16_t*)(ws + 192 * MB);
  bf16_t* Vp   = (bf16_t*)(ws + 208 * MB);
  bf16_t* Gp   = (bf16_t*)(ws + 224 * MB);
  bf16_t* attn = (bf16_t*)(ws);  // aliases xb (dead after proj_gemm8)

  const int nblk = (N4X + 5 * N4W) / 256;  // 90112
  cvt_all<<<nblk, 256, 0, stream>>>(x, Wq, Wk, Wv, Wd, Wo,
                                    xb, Wqb, Wkb, Wvb, Wdb, Wob);
  proj_gemm8<<<dim3(512), 512, 0, stream>>>(xb, Wqb, bq, Wkb, bk, Wvb, bv,
                                            Wdb, bd, Qp, Kp, Vp, Gp);
  attn_kernel<<<dim3(1024), 256, 0, stream>>>(Qp, Kp, Vp, Gp, t, attn);
  out_gemm<<<dim3(16, 32), 256, 0, stream>>>(attn, Wob, bo, (float*)d_out);
}

// Round 2
// 730.077 us; speedup vs baseline: 1.1436x; 1.0370x over previous
//
#include <hip/hip_runtime.h>
#include <hip/hip_bf16.h>
#include <cstdint>
#include <cstddef>

typedef __bf16 bf16_t;
typedef __bf16 bf16x4 __attribute__((ext_vector_type(4)));
typedef __bf16 bf16x8 __attribute__((ext_vector_type(8)));
typedef float f32x4 __attribute__((ext_vector_type(4)));

#define D_EMB   4096
#define N_HEADS 32
#define HEAD_D  128
#define SEQ     64
#define NBATCH  32
#define MTOT    2048
#define MB      1048576ULL
#define N4X     2097152   // MTOT*D_EMB/4  (2^21)
#define N4W     4194304   // D_EMB*D_EMB/4 (2^22)

// ---------------- fused fp32 -> bf16 convert: x + 5 weights, one launch ----
__global__ __launch_bounds__(256) void cvt_all(
    const float* __restrict__ x,  const float* __restrict__ w0,
    const float* __restrict__ w1, const float* __restrict__ w2,
    const float* __restrict__ w3, const float* __restrict__ w4,
    bf16_t* __restrict__ xb, bf16_t* __restrict__ d0, bf16_t* __restrict__ d1,
    bf16_t* __restrict__ d2, bf16_t* __restrict__ d3, bf16_t* __restrict__ d4) {
  const int i = blockIdx.x * 256 + threadIdx.x;
  const float* s; bf16_t* d; int j;
  if (i < N4X) { s = x; d = xb; j = i; }
  else {
    const int r = i - N4X;
    const int wi = r >> 22;          // / N4W
    j = r & (N4W - 1);
    if (wi == 0)      { s = w0; d = d0; }
    else if (wi == 1) { s = w1; d = d1; }
    else if (wi == 2) { s = w2; d = d2; }
    else if (wi == 3) { s = w3; d = d3; }
    else              { s = w4; d = d4; }
  }
  const float4 v = ((const float4*)s)[j];
  bf16x4 o;
  o[0] = (bf16_t)v.x; o[1] = (bf16_t)v.y; o[2] = (bf16_t)v.z; o[3] = (bf16_t)v.w;
  ((bf16x4*)d)[j] = o;
}

// ---------------- async global->LDS (16B per lane) ----------------
__device__ __forceinline__ void lds_async16(void* lds, const void* gp) {
  __builtin_amdgcn_global_load_lds(
      (const __attribute__((address_space(1))) void*)gp,
      (__attribute__((address_space(3))) void*)lds, 16, 0, 0);
}

#define BARRIER() asm volatile("s_barrier" ::: "memory")
#define WAIT_VM(n) asm volatile("s_waitcnt vmcnt(" #n ")" ::: "memory")
#define SCHED_FENCE() __builtin_amdgcn_sched_barrier(0)

// =====================================================================
// Stage 1: fused 4-way projection GEMM — 256x256 tile, BK=64, 8 waves,
// double-buffered 128KiB LDS. Round-2 schedule: 2 regions / 2 barriers
// per K-tile (was 4 phases / 8 barriers), NO explicit lgkmcnt drains —
// frag reads are plain C++ LDS loads so the compiler emits counted
// lgkmcnt(N) and interleaves ds_read with MFMA (the round-1 asm
// lgkmcnt(0) per phase serialized the LDS and MFMA pipes -> 40% MfmaUtil).
//
// LDS swizzle unchanged (round-1 verified: SQ_LDS_BANK_CONFLICT == 0):
// physical = linear ^ (((linear>>7)&3)<<4), applied to the pre-permuted
// GLOBAL source for global_load_lds (linear dest) and to the ds_read
// addresses (both-sides involution, rule #21).
//
// Hazard proof per K-tile T (buf = T&1):
//  region 1: read B-frags(8) + A q0,q1(8) from buf; stage A(T+1)->buf^1
//            (buf^1 A-reads finished last tile, before entry barrier);
//            MFMA(0),(1) consume ALL B-frags; sched_barrier(0) pins the
//            MFMAs above the region barrier.
//  BARRIER   => every wave consumed its B-frags => B region of buf is dead.
//  region 2: read A q2,q3 from buf; stage B(T+2)->buf B region (now safe);
//            MFMA(2),(3); counted vmcnt.
//  vmcnt(4): outstanding = B(T+1)[4, issued T-1] + A(T+1)[4] + B(T+2)[4];
//            waits oldest 8 => A(T+1),B(T+1) landed, B(T+2) stays in
//            flight (never drained to 0 in the loop).
//  BARRIER   => cross-wave visibility of all landed stages (symmetric
//            vmcnt across waves + barrier).
// =====================================================================

#define READ_AQ(DST, Q)                                                     \
  do {                                                                      \
    _Pragma("unroll")                                                       \
    for (int mi = 0; mi < 2; ++mi) {                                        \
      _Pragma("unroll")                                                     \
      for (int ks = 0; ks < 2; ++ks) {                                      \
        DST[mi][ks] =                                                       \
            *(const bf16x8*)(As + aoff + ((Q) * 2 + mi) * 1024 + ks * 16384); \
      }                                                                     \
    }                                                                       \
  } while (0)

#define MFMA_Q(Q, AFR)                                                      \
  do {                                                                      \
    _Pragma("unroll")                                                       \
    for (int mi = 0; mi < 2; ++mi) {                                        \
      _Pragma("unroll")                                                     \
      for (int j = 0; j < 4; ++j) {                                         \
        _Pragma("unroll")                                                   \
        for (int ks = 0; ks < 2; ++ks) {                                    \
          acc[(Q) * 2 + mi][j] = __builtin_amdgcn_mfma_f32_16x16x32_bf16(   \
              AFR[mi][ks], bfr[j][ks], acc[(Q) * 2 + mi][j], 0, 0, 0);      \
        }                                                                   \
      }                                                                     \
    }                                                                       \
  } while (0)

__global__ __launch_bounds__(512, 2) void proj_gemm8(
    const bf16_t* __restrict__ x,
    const bf16_t* __restrict__ Wq, const float* __restrict__ bq,
    const bf16_t* __restrict__ Wk, const float* __restrict__ bk,
    const bf16_t* __restrict__ Wv, const float* __restrict__ bv_,
    const bf16_t* __restrict__ Wd, const float* __restrict__ bd,
    bf16_t* __restrict__ Qp, bf16_t* __restrict__ Kp,
    bf16_t* __restrict__ Vp, bf16_t* __restrict__ Gp) {
  __shared__ __align__(16) char smem[131072];

  const int tid  = threadIdx.x;
  const int lane = tid & 63;
  const int wave = tid >> 6;
  const int quad = lane >> 4, l16 = lane & 15;
  const int wm = wave >> 2, wn = wave & 3;   // 2x4 wave grid -> 128x64 per wave

  // XCD-aware swizzle over the 512-block grid (512 % 8 == 0 -> bijective)
  const int bid = (int)blockIdx.x;
  const int sw  = ((bid & 7) << 6) | (bid >> 3);
  const int mt  = sw & 7;          // 8 m-tiles
  const int nt  = sw >> 3;         // 64 n-tiles (4 mats x 16)
  const int m0  = mt << 8;
  const int mat = nt >> 4;
  const int n0  = (nt & 15) << 8;

  const bf16_t* Bw; const float* bias; bf16_t* dst;
  if (mat == 0)      { Bw = Wq; bias = bq;  dst = Qp; }
  else if (mat == 1) { Bw = Wk; bias = bk;  dst = Kp; }
  else if (mat == 2) { Bw = Wv; bias = bv_; dst = Vp; }
  else               { Bw = Wd; bias = bd;  dst = Gp; }

  // ---- staging addressing: per-thread 2 chunks of 16B per 16KB region ----
  const int p0 = tid * 16, p1 = p0 + 8192;
  const int o0 = p0 ^ (((p0 >> 7) & 3) << 4);
  const int o1 = p1 ^ (((p1 >> 7) & 3) << 4);
  const char* gA0 = (const char*)(x  + (size_t)(m0 + (o0 >> 6)) * D_EMB) + (o0 & 63);
  const char* gA1 = (const char*)(x  + (size_t)(m0 + (o1 >> 6)) * D_EMB) + (o1 & 63);
  const char* gB0 = (const char*)(Bw + (size_t)(n0 + (o0 >> 6)) * D_EMB) + (o0 & 63);
  const char* gB1 = (const char*)(Bw + (size_t)(n0 + (o1 >> 6)) * D_EMB) + (o1 & 63);

  auto stageA = [&](int nb, int ks, int kbyte) {
    char* d = smem + nb * 65536 + ks * 16384;
    lds_async16(d + p0, gA0 + kbyte + ks * 64);
    lds_async16(d + p1, gA1 + kbyte + ks * 64);
  };
  auto stageB = [&](int nb, int ks, int kbyte) {
    char* d = smem + nb * 65536 + 32768 + ks * 16384;
    lds_async16(d + p0, gB0 + kbyte + ks * 64);
    lds_async16(d + p1, gB1 + kbyte + ks * 64);
  };

  // ---- LDS read offsets (swizzle folds to a per-lane constant) ----
  const int qsw  = (quad << 4) ^ ((l16 & 6) << 3);
  const int aoff = (wm * 128 + l16) * 64 + qsw;            // + mi*1024 + ks*16384
  const int boff = 32768 + (wn * 64 + l16) * 64 + qsw;     // + j*1024 + ks*16384

  f32x4 acc[8][4];
  const f32x4 zero = {0.f, 0.f, 0.f, 0.f};
#pragma unroll
  for (int i = 0; i < 8; ++i)
#pragma unroll
    for (int j = 0; j < 4; ++j) acc[i][j] = zero;

  // ---- prologue: tile0 fully + tile1's B; allow B(1) (4 loads) in flight ----
  stageA(0, 0, 0); stageA(0, 1, 0);
  stageB(0, 0, 0); stageB(0, 1, 0);
  stageB(1, 0, 128); stageB(1, 1, 128);
  WAIT_VM(4);
  BARRIER();

  bf16x8 bfr[4][2], afr0[2][2], afr1[2][2];

#pragma unroll 1
  for (int T = 0; T < 64; ++T) {
    const int buf = T & 1;
    const char* As = smem + buf * 65536;
    const int kb1 = (T + 1) << 7;   // byte offset of K-tile T+1
    const int kb2 = (T + 2) << 7;

    // ---------- region 1: B-frags + A q0,q1; stage A(T+1); MFMA(0),(1)
#pragma unroll
    for (int j = 0; j < 4; ++j)
#pragma unroll
      for (int ks = 0; ks < 2; ++ks)
        bfr[j][ks] = *(const bf16x8*)(As + boff + j * 1024 + ks * 16384);
    READ_AQ(afr0, 0);
    READ_AQ(afr1, 1);
    if (T < 63) { stageA(buf ^ 1, 0, kb1); stageA(buf ^ 1, 1, kb1); }
    __builtin_amdgcn_s_setprio(1);
    MFMA_Q(0, afr0);
    MFMA_Q(1, afr1);
    __builtin_amdgcn_s_setprio(0);
    SCHED_FENCE();          // pin MFMAs (and their lgkm waits) above barrier
    BARRIER();              // all waves consumed B-frags -> B region dead

    // ---------- region 2: A q2,q3; stage B(T+2) into buf; MFMA(2),(3)
    READ_AQ(afr0, 2);
    READ_AQ(afr1, 3);
    if (T < 62) { stageB(buf, 0, kb2); stageB(buf, 1, kb2); }
    __builtin_amdgcn_s_setprio(1);
    MFMA_Q(2, afr0);
    MFMA_Q(3, afr1);
    __builtin_amdgcn_s_setprio(0);
    SCHED_FENCE();          // pin MFMAs above the tile-boundary barrier
    if (T < 62) { WAIT_VM(4); } else { WAIT_VM(0); }
    BARRIER();
  }

  // ---- epilogue: bias (+sigmoid for gamma), store bf16 ----
  const bool is_g = (mat == 3);
#pragma unroll
  for (int j = 0; j < 4; ++j) {
    const int col = n0 + wn * 64 + j * 16 + l16;
    const float bb = bias[col];
#pragma unroll
    for (int mi = 0; mi < 8; ++mi) {
      const int rowb = m0 + wm * 128 + mi * 16 + quad * 4;
#pragma unroll
      for (int r = 0; r < 4; ++r) {
        float v = acc[mi][j][r] + bb;
        if (is_g) v = 1.0f / (1.0f + __expf(-v));
        dst[(size_t)(rowb + r) * D_EMB + col] = (bf16_t)v;
      }
    }
  }
}

// ---------------- m97-style bt-GEMM core: C[128x128] tile (out_gemm) -------
__device__ __forceinline__ void gemm_core_bt(const bf16_t* __restrict__ A,
                                             const bf16_t* __restrict__ B,
                                             int K, int m0, int n0,
                                             bf16_t* As, bf16_t* Bs,
                                             f32x4 acc[4][4]) {
  const int tid  = threadIdx.x;
  const int lane = tid & 63;
  const int wave = tid >> 6;
  const int quad = lane >> 4;
  const int l16  = lane & 15;
  const int wm   = (wave >> 1) * 64;
  const int wn   = (wave & 1) * 64;

  const int q0 = tid;
  const int q1 = tid + 256;
  const int r0 = q0 >> 2, c0 = (q0 & 3) * 8;
  const int r1 = q1 >> 2, c1 = (q1 & 3) * 8;

  const bf16_t* Arow0 = A + (size_t)(m0 + r0) * K + c0;
  const bf16_t* Arow1 = A + (size_t)(m0 + r1) * K + c1;
  const bf16_t* Brow0 = B + (size_t)(n0 + r0) * K + c0;
  const bf16_t* Brow1 = B + (size_t)(n0 + r1) * K + c1;

  for (int k0 = 0; k0 < K; k0 += 32) {
    lds_async16(As + q0 * 8, Arow0 + k0);
    lds_async16(As + q1 * 8, Arow1 + k0);
    lds_async16(Bs + q0 * 8, Brow0 + k0);
    lds_async16(Bs + q1 * 8, Brow1 + k0);
    __syncthreads();

    bf16x8 af[4], bfv[4];
#pragma unroll
    for (int i = 0; i < 4; i++)
      af[i] = *(const bf16x8*)&As[(wm + 16 * i + l16) * 32 + quad * 8];
#pragma unroll
    for (int j = 0; j < 4; j++)
      bfv[j] = *(const bf16x8*)&Bs[(wn + 16 * j + l16) * 32 + quad * 8];
#pragma unroll
    for (int i = 0; i < 4; i++)
#pragma unroll
      for (int j = 0; j < 4; j++)
        acc[i][j] = __builtin_amdgcn_mfma_f32_16x16x32_bf16(af[i], bfv[j],
                                                            acc[i][j], 0, 0, 0);
    __syncthreads();
  }
}

// ---------------- Stage 2: per-(b,h) RoPE + decay + attention (MFMA) -------
__global__ __launch_bounds__(256) void attn_kernel(
    const bf16_t* __restrict__ Qp, const bf16_t* __restrict__ Kp,
    const bf16_t* __restrict__ Vp, const bf16_t* __restrict__ Gp,
    const float* __restrict__ t, bf16_t* __restrict__ attn) {
  __shared__ __align__(16) char smem[65536];
  bf16_t* Qs  = (bf16_t*)smem;              // [64][128] rope(Q)
  bf16_t* Ks  = (bf16_t*)(smem + 16384);    // [64][128] rope(K)
  bf16_t* Gs  = (bf16_t*)(smem + 32768);    // [64][128] gc
  bf16_t* IGs = (bf16_t*)(smem + 49152);    // [64][128] 1/gc
  // phase-3 overlay (over Gs/IGs):
  bf16_t* Ps  = (bf16_t*)(smem + 32768);           // [64][72] decayed, bf16
  bf16_t* Vt  = (bf16_t*)(smem + 32768 + 9216);    // [128][72] V transposed

  const int tid = threadIdx.x;
  const int lane = tid & 63, wv = tid >> 6;
  const int quad = lane >> 4, l16 = lane & 15;
  const int b = blockIdx.x >> 5, h = blockIdx.x & 31;
  const size_t base = (size_t)(b * SEQ) * D_EMB + (size_t)h * HEAD_D;

  for (int idx = tid; idx < SEQ * HEAD_D; idx += 256) {
    const int s = idx >> 7, d = idx & 127;
    const float invf = __expf(-0.14391156831212787f * (float)s);
    const float theta = t[d & 63] * invf;
    float sn, cs;
    __sincosf(theta, &sn, &cs);
    const size_t po = base + (size_t)s * D_EMB;
    {
      const float v = (float)Qp[po + d];
      const float o = (float)Qp[po + (d ^ 64)];
      const float rot = (d < 64) ? -o : o;
      Qs[idx] = (bf16_t)(v * cs + rot * sn);
    }
    {
      const float v = (float)Kp[po + d];
      const float o = (float)Kp[po + (d ^ 64)];
      const float rot = (d < 64) ? -o : o;
      Ks[idx] = (bf16_t)(v * cs + rot * sn);
    }
  }
  if (tid < HEAD_D) {
    const int d = tid;
    float run = 1.0f;
    for (int s = 0; s < SEQ; s++) {
      run *= (float)Gp[base + (size_t)s * D_EMB + d];
      Gs[s * HEAD_D + d]  = (bf16_t)run;
      IGs[s * HEAD_D + d] = (bf16_t)(1.0f / run);
    }
  }
  __syncthreads();

  f32x4 Sa[4], Da[4];
  const f32x4 zero = {0.f, 0.f, 0.f, 0.f};
#pragma unroll
  for (int j = 0; j < 4; j++) { Sa[j] = zero; Da[j] = zero; }

  for (int k0 = 0; k0 < HEAD_D; k0 += 32) {
    const bf16x8 aq = *(const bf16x8*)&Qs[(wv * 16 + l16) * HEAD_D + quad * 8 + k0];
    const bf16x8 ag = *(const bf16x8*)&Gs[(wv * 16 + l16) * HEAD_D + quad * 8 + k0];
#pragma unroll
    for (int j = 0; j < 4; j++) {
      const bf16x8 bk = *(const bf16x8*)&Ks [(16 * j + l16) * HEAD_D + quad * 8 + k0];
      const bf16x8 bg = *(const bf16x8*)&IGs[(16 * j + l16) * HEAD_D + quad * 8 + k0];
      Sa[j] = __builtin_amdgcn_mfma_f32_16x16x32_bf16(aq, bk, Sa[j], 0, 0, 0);
      Da[j] = __builtin_amdgcn_mfma_f32_16x16x32_bf16(ag, bg, Da[j], 0, 0, 0);
    }
  }
  __syncthreads();

#pragma unroll
  for (int j = 0; j < 4; j++) {
#pragma unroll
    for (int r = 0; r < 4; r++) {
      const int q = wv * 16 + quad * 4 + r;
      const int k = 16 * j + l16;
      const float v = (k <= q) ? Sa[j][r] * Da[j][r] * 0.0078125f : 0.0f;
      Ps[q * 72 + k] = (bf16_t)v;
    }
  }
  for (int idx = tid; idx < SEQ * HEAD_D; idx += 256) {
    const int s = idx >> 7, d = idx & 127;
    Vt[d * 72 + s] = Vp[base + (size_t)s * D_EMB + d];
  }
  __syncthreads();

  f32x4 oa[8];
#pragma unroll
  for (int j = 0; j < 8; j++) oa[j] = zero;
  for (int k0 = 0; k0 < SEQ; k0 += 32) {
    const bf16x8 ap = *(const bf16x8*)&Ps[(wv * 16 + l16) * 72 + quad * 8 + k0];
#pragma unroll
    for (int j = 0; j < 8; j++) {
      const bf16x8 bv = *(const bf16x8*)&Vt[(16 * j + l16) * 72 + quad * 8 + k0];
      oa[j] = __builtin_amdgcn_mfma_f32_16x16x32_bf16(ap, bv, oa[j], 0, 0, 0);
    }
  }
#pragma unroll
  for (int j = 0; j < 8; j++) {
#pragma unroll
    for (int r = 0; r < 4; r++) {
      const int q = wv * 16 + quad * 4 + r;
      attn[(size_t)(b * SEQ + q) * D_EMB + (size_t)h * HEAD_D + 16 * j + l16] =
          (bf16_t)oa[j][r];
    }
  }
}

// ---------------- Stage 3: output projection GEMM (fp32 out) ----------------
__global__ __launch_bounds__(256) void out_gemm(
    const bf16_t* __restrict__ A, const bf16_t* __restrict__ Wo,
    const float* __restrict__ bo, float* __restrict__ out) {
  __shared__ __align__(16) bf16_t As[128 * 32];
  __shared__ __align__(16) bf16_t Bs[128 * 32];

  const int m0 = blockIdx.x * 128;
  const int n0 = blockIdx.y * 128;

  f32x4 acc[4][4];
  const f32x4 zero = {0.f, 0.f, 0.f, 0.f};
#pragma unroll
  for (int i = 0; i < 4; i++)
#pragma unroll
    for (int j = 0; j < 4; j++) acc[i][j] = zero;

  gemm_core_bt(A, Wo, D_EMB, m0, n0, As, Bs, acc);

  const int tid = threadIdx.x, lane = tid & 63, wave = tid >> 6;
  const int quad = lane >> 4, l16 = lane & 15;
  const int wm = (wave >> 1) * 64, wn = (wave & 1) * 64;

#pragma unroll
  for (int i = 0; i < 4; i++) {
#pragma unroll
    for (int j = 0; j < 4; j++) {
      const int col = n0 + wn + 16 * j + l16;
      const float bv_ = bo[col];
      const int rowb = m0 + wm + 16 * i + quad * 4;
#pragma unroll
      for (int r = 0; r < 4; r++)
        out[(size_t)(rowb + r) * D_EMB + col] = acc[i][j][r] + bv_;
    }
  }
}

// ---------------- launch ----------------
extern "C" void kernel_launch(void* const* d_in, const int* in_sizes, int n_in,
                              void* d_out, int out_size, void* d_ws, size_t ws_size,
                              hipStream_t stream) {
  const float* x  = (const float*)d_in[0];
  const float* t  = (const float*)d_in[1];
  const float* Wq = (const float*)d_in[2];
  const float* bq = (const float*)d_in[3];
  const float* Wk = (const float*)d_in[4];
  const float* bk = (const float*)d_in[5];
  const float* Wv = (const float*)d_in[6];
  const float* bv = (const float*)d_in[7];
  const float* Wd = (const float*)d_in[8];
  const float* bd = (const float*)d_in[9];
  const float* Wo = (const float*)d_in[10];
  const float* bo = (const float*)d_in[11];

  char* ws = (char*)d_ws;
  bf16_t* xb   = (bf16_t*)(ws);
  bf16_t* Wqb  = (bf16_t*)(ws + 16 * MB);
  bf16_t* Wkb  = (bf16_t*)(ws + 48 * MB);
  bf16_t* Wvb  = (bf16_t*)(ws + 80 * MB);
  bf16_t* Wdb  = (bf16_t*)(ws + 112 * MB);
  bf16_t* Wob  = (bf16_t*)(ws + 144 * MB);
  bf16_t* Qp   = (bf16_t*)(ws + 176 * MB);
  bf16_t* Kp   = (bf16_t*)(ws + 192 * MB);
  bf16_t* Vp   = (bf16_t*)(ws + 208 * MB);
  bf16_t* Gp   = (bf16_t*)(ws + 224 * MB);
  bf16_t* attn = (bf16_t*)(ws);  // aliases xb (dead after proj_gemm8)

  const int nblk = (N4X + 5 * N4W) / 256;  // 90112
  cvt_all<<<nblk, 256, 0, stream>>>(x, Wq, Wk, Wv, Wd, Wo,
                                    xb, Wqb, Wkb, Wvb, Wdb, Wob);
  proj_gemm8<<<dim3(512), 512, 0, stream>>>(xb, Wqb, bq, Wkb, bk, Wvb, bv,
                                            Wdb, bd, Qp, Kp, Vp, Gp);
  attn_kernel<<<dim3(1024), 256, 0, stream>>>(Qp, Kp, Vp, Gp, t, attn);
  out_gemm<<<dim3(16, 32), 256, 0, stream>>>(attn, Wob, bo, (float*)d_out);
}